// Round 10
// baseline (462.659 us; speedup 1.0000x reference)
//
#include <hip/hip_runtime.h>
#include <math.h>

#define Bn   64
#define Ln   4096
#define LQn  128
#define Dn   32
#define ETn  128
#define Hn   128
#define G3n  384
#define NDEG 12

typedef __attribute__((ext_vector_type(2))) float f32x2;

// DPP helpers (VALU cross-lane, no LDS pipe)
#define DPPF(x, ctrl) __int_as_float(__builtin_amdgcn_update_dpp(0, __float_as_int(x), (ctrl), 0xF, 0xF, true))
#define QP_XOR1 0xB1   // quad_perm [1,0,3,2]
#define QP_XOR2 0x4E   // quad_perm [2,3,0,1]
#define QP_B0   0x00
#define QP_B1   0x55
#define QP_B2   0xAA
#define QP_B3   0xFF

// odd sin polynomial, |x| <= ~0.5, err < 5e-9
__device__ __forceinline__ float sin_poly(float x) {
    const float x2 = x * x;
    float r = -1.9841270114e-04f;
    r = fmaf(r, x2,  8.3333337680e-03f);
    r = fmaf(r, x2, -1.6666667163e-01f);
    return fmaf(r * x2, x, x);
}
// even cos polynomial, |x| <= ~0.5, err < 3e-10
__device__ __forceinline__ float cos_poly(float x) {
    const float x2 = x * x;
    float r =  2.4801587642e-05f;
    r = fmaf(r, x2, -1.3888888899e-03f);
    r = fmaf(r, x2,  4.1666667908e-02f);
    r = fmaf(r, x2, -5.0000000000e-01f);
    return fmaf(r, x2, 1.0f);
}

// ---- workspace layout (float offsets) ----
#define WS_C    0                          // 128*12
#define WS_WT   4096                       // 768*32
#define WS_B2   (WS_WT + 768*32)           // 768 (pad 1024)
#define WS_CLS  (WS_B2 + 1024)             // 64*256
#define WS_G0   (WS_CLS + Bn*2*Hn)         // 8192*256  (transient aliases below)
#define WS_GI   (WS_G0 + Bn*LQn*2*Hn)      // 8192*768
// transient aliases inside WS_G0 (dead before the region's next use):
#define WS_QPB  WS_G0                      // 128*128 qp matrix (k_qp -> k_qtc)
#define WS_BAS  (WS_G0 + 16384)            // 12*128 basis     (k_basis -> k_qtc)
#define WS_ACCP WS_G0                      // 4*8192*32 (k_attn -> k_gemm_att)
#define WS_SP   (WS_G0 + 1048576)          // 4*8192

// =================== K1a: basis[d][j] = pw_j^d/d! * phase(pb_j, d) ===================
__global__ __launch_bounds__(128) void k_basis(
    const float* __restrict__ per_w, const float* __restrict__ per_b,
    float* __restrict__ basis)
{
    const int j = threadIdx.x;
    if (j >= ETn - 1) return;
    const float w = per_w[j], b = per_b[j];
    const float sb = sin_poly(b), cb = cos_poly(b);
    float wp = 1.f;
#pragma unroll
    for (int d = 0; d < NDEG; ++d) {
        const float sd = ((d & 3) == 0) ? sb : ((d & 3) == 1) ? cb : ((d & 3) == 2) ? -sb : -cb;
        basis[d * 128 + j] = wp * sd;
        wp *= w / (float)(d + 1);
    }
}

// =================== K1b: qp[q][e] = sum_i qe[q][i]*wq[i][e] + bq[e] ===================
__global__ __launch_bounds__(128) void k_qp(
    const float* __restrict__ qtimes, const float* __restrict__ lin_w,
    const float* __restrict__ lin_b, const float* __restrict__ per_w,
    const float* __restrict__ per_b, const float* __restrict__ wq,
    const float* __restrict__ bq, float* __restrict__ qp)
{
    __shared__ float qe[ETn];
    const int q = blockIdx.x, e = threadIdx.x;
    const float t = qtimes[q];
    qe[e] = (e == 0) ? fmaf(t, lin_w[0], lin_b[0])
                     : sin_poly(fmaf(t, per_w[e - 1], per_b[e - 1]));
    __syncthreads();
    float a = bq[e];
#pragma unroll 16
    for (int i = 0; i < ETn; ++i) a = fmaf(qe[i], wq[i * ETn + e], a);
    qp[q * ETn + e] = a;
}

// =================== K1c: qt + coefficients C[q][d] ===================
__global__ __launch_bounds__(128) void k_qtc(
    const float* __restrict__ qp, const float* __restrict__ wk,
    const float* __restrict__ bk, const float* __restrict__ lin_w,
    const float* __restrict__ lin_b, const float* __restrict__ basis,
    float* __restrict__ C)
{
    __shared__ float qp_l[ETn], qt_l[ETn], red[96], qbk_red[32];
    const int q = blockIdx.x, tid = threadIdx.x;
    qp_l[tid] = qp[q * ETn + tid];
    __syncthreads();
    {
        const float4* wk4 = (const float4*)(wk + (size_t)tid * ETn);
        const float4* qp4 = (const float4*)qp_l;
        float a = 0.f;
#pragma unroll
        for (int k = 0; k < 32; ++k) {
            const float4 w4 = wk4[k], p4 = qp4[k];
            a += w4.x * p4.x + w4.y * p4.y + w4.z * p4.z + w4.w * p4.w;
        }
        qt_l[tid] = a;
    }
    __syncthreads();
    if (tid < 96) {
        const int d = tid >> 3, g = tid & 7;
        float p = 0.f;
        for (int j = g; j < ETn - 1; j += 8) p = fmaf(qt_l[j + 1], basis[d * 128 + j], p);
        red[tid] = p;
    } else {
        const int g2 = tid - 96;
        float p = 0.f;
#pragma unroll
        for (int k = 0; k < 4; ++k) p = fmaf(qp_l[g2 + 32 * k], bk[g2 + 32 * k], p);
        qbk_red[g2] = p;
    }
    __syncthreads();
    if (tid < NDEG) {
        const int d = tid;
        float s = red[d * 8 + 0] + red[d * 8 + 1] + red[d * 8 + 2] + red[d * 8 + 3]
                + red[d * 8 + 4] + red[d * 8 + 5] + red[d * 8 + 6] + red[d * 8 + 7];
        if (d == 0) {
            float qbk = 0.f;
#pragma unroll
            for (int k = 0; k < 32; ++k) qbk += qbk_red[k];
            s += qt_l[0] * lin_b[0] + qbk;
        }
        if (d == 1) s += qt_l[0] * lin_w[0];
        C[q * NDEG + d] = s * 0.08838834764831845f;   // 1/sqrt(128)
    }
}

// =================== K1d: fold wo (+bo) into layer-0 wih ===================
__global__ __launch_bounds__(256) void k_fuse(
    const float* __restrict__ wih, const float* __restrict__ wo,
    const float* __restrict__ bo, const float* __restrict__ bih,
    float* __restrict__ Wt, float* __restrict__ bias2)
{
    const int t = blockIdx.x * 256 + threadIdx.x;
    if (t < 768 * 32) {
        const int o = t >> 5, d = t & 31;
        const float* wr = wih + (size_t)o * 128;
        const float* wc = wo + (size_t)d * 128;
        float a = 0.f;
        for (int h = 0; h < 128; ++h) a += wr[h] * wc[h];
        Wt[t] = a;
    } else if (t < 768 * 33) {
        const int o = t - 768 * 32;
        const float* wr = wih + (size_t)o * 128;
        float a = bih[o];
        for (int h = 0; h < 128; ++h) a += bo[h] * wr[h];
        bias2[o] = a;
    }
}

// =================== K2: attention, unnormalized (no max-sub: |score| <= ~6) ===================
#define ACC8(m, pv) \
    acc[m][0].x = fmaf(pv, xa.x, acc[m][0].x); acc[m][0].y = fmaf(pv, xa.y, acc[m][0].y); \
    acc[m][0].z = fmaf(pv, xa.z, acc[m][0].z); acc[m][0].w = fmaf(pv, xa.w, acc[m][0].w); \
    acc[m][1].x = fmaf(pv, xb.x, acc[m][1].x); acc[m][1].y = fmaf(pv, xb.y, acc[m][1].y); \
    acc[m][1].z = fmaf(pv, xb.z, acc[m][1].z); acc[m][1].w = fmaf(pv, xb.w, acc[m][1].w);

__global__ __launch_bounds__(512, 2) void k_attn(
    const float* __restrict__ x, const float* __restrict__ tsteps,
    const float* __restrict__ Cc, float* __restrict__ accP, float* __restrict__ sP)
{
    __shared__ float slab[4][128][36];
    const int tid = threadIdx.x;
    const int b = blockIdx.x >> 2, lsplit = blockIdx.x & 3;
    const int i = tid & 3, qt = (tid >> 2) & 31, ls2 = tid >> 7;
    const int qown = 4 * qt + i;

    float c[NDEG];
#pragma unroll
    for (int d = 0; d < NDEG; ++d) c[d] = Cc[qown * NDEG + d];

    const int l0 = lsplit * 1024 + ls2 * 256;
    const float4* tg4 = (const float4*)(tsteps + (size_t)b * Ln + l0);
    const float4* xg  = (const float4*)(x + ((size_t)b * Ln + l0) * Dn);

    float4 acc[4][2];
#pragma unroll
    for (int m = 0; m < 4; ++m)
#pragma unroll
        for (int e = 0; e < 2; ++e) { acc[m][e].x = 0.f; acc[m][e].y = 0.f; acc[m][e].z = 0.f; acc[m][e].w = 0.f; }
    float s_own = 0.f;

    for (int k = 0; k < 64; ++k) {
        const float4 t4 = tg4[k];
#pragma unroll
        for (int jj = 0; jj < 4; ++jj) {
            const float t = (jj == 0) ? t4.x : (jj == 1) ? t4.y : (jj == 2) ? t4.z : t4.w;
            float sc = c[NDEG - 1];
#pragma unroll
            for (int d = NDEG - 2; d >= 0; --d) sc = fmaf(sc, t, c[d]);
            const float pe = __expf(sc);
            s_own += pe;
            const float p0 = DPPF(pe, QP_B0);
            const float p1 = DPPF(pe, QP_B1);
            const float p2 = DPPF(pe, QP_B2);
            const float p3 = DPPF(pe, QP_B3);
            const int lrow = (k * 4 + jj) * 8;
            const float4 xa = xg[lrow + 2 * i];
            const float4 xb = xg[lrow + 2 * i + 1];
            ACC8(0, p0) ACC8(1, p1) ACC8(2, p2) ACC8(3, p3)
        }
    }
#pragma unroll
    for (int m = 0; m < 4; ++m) {
        *(float4*)&slab[ls2][4 * qt + m][8 * i]     = acc[m][0];
        *(float4*)&slab[ls2][4 * qt + m][8 * i + 4] = acc[m][1];
    }
    slab[ls2][qown][32] = s_own;
    __syncthreads();
    const int q = tid & 127, part = tid >> 7;
#pragma unroll
    for (int j = 0; j < 2; ++j) {
        const int off = (part * 2 + j) * 4;
        float4 r  = *(float4*)&slab[0][q][off];
        float4 r1 = *(float4*)&slab[1][q][off];
        float4 r2 = *(float4*)&slab[2][q][off];
        float4 r3 = *(float4*)&slab[3][q][off];
        r.x += r1.x + r2.x + r3.x; r.y += r1.y + r2.y + r3.y;
        r.z += r1.z + r2.z + r3.z; r.w += r1.w + r2.w + r3.w;
        *(float4*)&accP[((((size_t)lsplit * Bn + b) * LQn + q) * 32) + off] = r;
    }
    if (part == 0) {
        sP[((size_t)lsplit * Bn + b) * LQn + q] =
            slab[0][q][32] + slab[1][q][32] + slab[2][q][32] + slab[3][q][32];
    }
}

// =================== K3a: GEMM layer-0: A = (sum_ls accP)/(sum_ls sP), K=32 ===================
__global__ __launch_bounds__(256) void k_gemm_att(
    const float* __restrict__ accP, const float* __restrict__ sP,
    const float* __restrict__ Bm, const float* __restrict__ bias,
    float* __restrict__ Cm)
{
    __shared__ float4 A_l[64 * 8];
    __shared__ float4 B_l[64 * 8];
    const int tid = threadIdx.x;
    const int m0 = blockIdx.x * 64, n0 = blockIdx.y * 64;
    const int r0 = (tid >> 4) << 2, c0 = (tid & 15) << 2;
    float acc[4][4] = {};
    const float4* Ag = (const float4*)accP;
    const float4* Bg = (const float4*)Bm;

#pragma unroll
    for (int w = 0; w < 2; ++w) {
        const int idx = tid + w * 256;
        const int row = idx >> 3, c4 = idx & 7;
        const int sc = (c4 + row + (row >> 2)) & 7;
        const int m = m0 + row;
        float4 a0 = Ag[(size_t)m * 8 + c4];
        float4 a1 = Ag[((size_t)8192  + m) * 8 + c4];
        float4 a2 = Ag[((size_t)16384 + m) * 8 + c4];
        float4 a3 = Ag[((size_t)24576 + m) * 8 + c4];
        const float inv = 1.f / (sP[m] + sP[8192 + m] + sP[16384 + m] + sP[24576 + m]);
        float4 av;
        av.x = (a0.x + a1.x + a2.x + a3.x) * inv;
        av.y = (a0.y + a1.y + a2.y + a3.y) * inv;
        av.z = (a0.z + a1.z + a2.z + a3.z) * inv;
        av.w = (a0.w + a1.w + a2.w + a3.w) * inv;
        A_l[row * 8 + sc] = av;
        B_l[row * 8 + sc] = Bg[(size_t)(n0 + row) * 8 + c4];
    }
    __syncthreads();
#pragma unroll
    for (int k4 = 0; k4 < 8; ++k4) {
        float4 av[4], bv[4];
#pragma unroll
        for (int j = 0; j < 4; ++j) {
            const int ra = r0 + j;
            av[j] = A_l[ra * 8 + ((k4 + ra + (ra >> 2)) & 7)];
        }
#pragma unroll
        for (int j = 0; j < 4; ++j) {
            const int rb = c0 + j;
            bv[j] = B_l[rb * 8 + ((k4 + rb + (rb >> 2)) & 7)];
        }
#pragma unroll
        for (int ri = 0; ri < 4; ++ri)
#pragma unroll
            for (int ci = 0; ci < 4; ++ci)
                acc[ri][ci] += av[ri].x * bv[ci].x + av[ri].y * bv[ci].y
                             + av[ri].z * bv[ci].z + av[ri].w * bv[ci].w;
    }
#pragma unroll
    for (int ri = 0; ri < 4; ++ri) {
        float4 o4;
        o4.x = acc[ri][0] + bias[n0 + c0 + 0];
        o4.y = acc[ri][1] + bias[n0 + c0 + 1];
        o4.z = acc[ri][2] + bias[n0 + c0 + 2];
        o4.w = acc[ri][3] + bias[n0 + c0 + 3];
        *(float4*)&Cm[(size_t)(m0 + r0 + ri) * 768 + n0 + c0] = o4;
    }
}

// =================== K3b: tiled f32 GEMM  C = A(MxK) @ B(NxK)^T + bias ===================
__global__ __launch_bounds__(256) void k_gemm_nt(
    const float* __restrict__ A, const float* __restrict__ Bm,
    const float* __restrict__ bias, float* __restrict__ Cm,
    int N, int K)
{
    __shared__ float4 A_l[64 * 8];
    __shared__ float4 B_l[64 * 8];
    const int tid = threadIdx.x;
    const int m0 = blockIdx.x * 64, n0 = blockIdx.y * 64;
    const int r0 = (tid >> 4) << 2, c0 = (tid & 15) << 2;
    const int K4 = K >> 2;
    float acc[4][4] = {};
    const float4* Ag = (const float4*)A;
    const float4* Bg = (const float4*)Bm;

    for (int k0 = 0; k0 < K4; k0 += 8) {
        __syncthreads();
#pragma unroll
        for (int w = 0; w < 2; ++w) {
            const int idx = tid + w * 256;
            const int row = idx >> 3, c4 = idx & 7;
            const int sc = (c4 + row + (row >> 2)) & 7;
            A_l[row * 8 + sc] = Ag[(size_t)(m0 + row) * K4 + k0 + c4];
            B_l[row * 8 + sc] = Bg[(size_t)(n0 + row) * K4 + k0 + c4];
        }
        __syncthreads();
#pragma unroll
        for (int k4 = 0; k4 < 8; ++k4) {
            float4 av[4], bv[4];
#pragma unroll
            for (int j = 0; j < 4; ++j) {
                const int ra = r0 + j;
                av[j] = A_l[ra * 8 + ((k4 + ra + (ra >> 2)) & 7)];
            }
#pragma unroll
            for (int j = 0; j < 4; ++j) {
                const int rb = c0 + j;
                bv[j] = B_l[rb * 8 + ((k4 + rb + (rb >> 2)) & 7)];
            }
#pragma unroll
            for (int ri = 0; ri < 4; ++ri)
#pragma unroll
                for (int ci = 0; ci < 4; ++ci)
                    acc[ri][ci] += av[ri].x * bv[ci].x + av[ri].y * bv[ci].y
                                 + av[ri].z * bv[ci].z + av[ri].w * bv[ci].w;
        }
    }
#pragma unroll
    for (int ri = 0; ri < 4; ++ri) {
        float4 o4;
        o4.x = acc[ri][0] + bias[n0 + c0 + 0];
        o4.y = acc[ri][1] + bias[n0 + c0 + 1];
        o4.z = acc[ri][2] + bias[n0 + c0 + 2];
        o4.w = acc[ri][3] + bias[n0 + c0 + 3];
        *(float4*)&Cm[(size_t)(m0 + r0 + ri) * N + n0 + c0] = o4;
    }
}

// =================== K4: GRU recurrence — weights in explicit physical AGPRs ===================
// 512 threads: (j = tid>>2 in [0,128), q = tid&3 = 32-wide h-slice). One block per (b,dir).
// 96 weight floats per lane live in a0..a95 (hard-coded v_accvgpr_write/read — the VGPR
// allocator cannot see, remat, or spill them). Per step: 96 accvgpr_read + 48 pk_fma.
#define AST(s, v) { float t_ = (v); \
    asm volatile("v_accvgpr_write_b32 a" s ", %0" :: "v"(t_) : "a" s); }
#define AMAC(s0, s1, hp, acc) { float t0_, t1_; \
    asm volatile("v_accvgpr_read_b32 %0, a" s0 : "=v"(t0_)); \
    asm volatile("v_accvgpr_read_b32 %0, a" s1 : "=v"(t1_)); \
    f32x2 w_; w_.x = t0_; w_.y = t1_; \
    acc = __builtin_elementwise_fma(w_, hp, acc); }

__global__ __launch_bounds__(512) void k_gru(
    const float* __restrict__ gi, const float* __restrict__ whh,
    const float* __restrict__ bhh, float* __restrict__ seq_out,
    float* __restrict__ final_out)
{
    __shared__ float h_l[2][4 * 36];
    const int tid = threadIdx.x;
    const int b = blockIdx.x >> 1, dir = blockIdx.x & 1;
    const int j = tid >> 2, q = tid & 3;

    // ---- stash weights in a0..a95: r -> a0-31, z -> a32-63, n -> a64-95 ----
    {
        const float* w0 = whh + ((size_t)dir * G3n + j) * Hn + 32 * q;
        const float* w1 = w0 + (size_t)128 * Hn;
        const float* w2 = w0 + (size_t)256 * Hn;
        AST("0",w0[0])  AST("1",w0[1])  AST("2",w0[2])  AST("3",w0[3])
        AST("4",w0[4])  AST("5",w0[5])  AST("6",w0[6])  AST("7",w0[7])
        AST("8",w0[8])  AST("9",w0[9])  AST("10",w0[10]) AST("11",w0[11])
        AST("12",w0[12]) AST("13",w0[13]) AST("14",w0[14]) AST("15",w0[15])
        AST("16",w0[16]) AST("17",w0[17]) AST("18",w0[18]) AST("19",w0[19])
        AST("20",w0[20]) AST("21",w0[21]) AST("22",w0[22]) AST("23",w0[23])
        AST("24",w0[24]) AST("25",w0[25]) AST("26",w0[26]) AST("27",w0[27])
        AST("28",w0[28]) AST("29",w0[29]) AST("30",w0[30]) AST("31",w0[31])
        AST("32",w1[0])  AST("33",w1[1])  AST("34",w1[2])  AST("35",w1[3])
        AST("36",w1[4])  AST("37",w1[5])  AST("38",w1[6])  AST("39",w1[7])
        AST("40",w1[8])  AST("41",w1[9])  AST("42",w1[10]) AST("43",w1[11])
        AST("44",w1[12]) AST("45",w1[13]) AST("46",w1[14]) AST("47",w1[15])
        AST("48",w1[16]) AST("49",w1[17]) AST("50",w1[18]) AST("51",w1[19])
        AST("52",w1[20]) AST("53",w1[21]) AST("54",w1[22]) AST("55",w1[23])
        AST("56",w1[24]) AST("57",w1[25]) AST("58",w1[26]) AST("59",w1[27])
        AST("60",w1[28]) AST("61",w1[29]) AST("62",w1[30]) AST("63",w1[31])
        AST("64",w2[0])  AST("65",w2[1])  AST("66",w2[2])  AST("67",w2[3])
        AST("68",w2[4])  AST("69",w2[5])  AST("70",w2[6])  AST("71",w2[7])
        AST("72",w2[8])  AST("73",w2[9])  AST("74",w2[10]) AST("75",w2[11])
        AST("76",w2[12]) AST("77",w2[13]) AST("78",w2[14]) AST("79",w2[15])
        AST("80",w2[16]) AST("81",w2[17]) AST("82",w2[18]) AST("83",w2[19])
        AST("84",w2[20]) AST("85",w2[21]) AST("86",w2[22]) AST("87",w2[23])
        AST("88",w2[24]) AST("89",w2[25]) AST("90",w2[26]) AST("91",w2[27])
        AST("92",w2[28]) AST("93",w2[29]) AST("94",w2[30]) AST("95",w2[31])
    }
    const float bhr = bhh[dir * G3n + j];
    const float bhz = bhh[dir * G3n + 128 + j];
    const float bhn = bhh[dir * G3n + 256 + j];

    if (tid < 144) h_l[0][tid] = 0.f;
    __syncthreads();

    const long sstride = dir ? -768 : 768;
    const float* gptr = gi + (size_t)b * LQn * 768 + dir * G3n + q * Hn + j
                        + (size_t)(dir ? LQn - 1 : 0) * 768;
    const int hslot = (j >> 5) * 36 + (j & 31);
    const bool ldq = (q < 3);

    int cur = 0;
    float hlast = 0.f;

    auto gstep = [&](const float gi_cur, const int step) {
        const float hold = h_l[cur][hslot];
        // h pairs for this lane's 32-slice
        const float4* hq = (const float4*)(&h_l[cur][q * 36]);
        f32x2 hp[16];
#pragma unroll
        for (int m = 0; m < 8; ++m) {
            const float4 hv = hq[m];
            hp[2 * m].x = hv.x;     hp[2 * m].y = hv.y;
            hp[2 * m + 1].x = hv.z; hp[2 * m + 1].y = hv.w;
        }
        f32x2 ar = {0.f, 0.f}, az = {0.f, 0.f}, an = {0.f, 0.f};
        AMAC("0","1",hp[0],ar)   AMAC("2","3",hp[1],ar)   AMAC("4","5",hp[2],ar)   AMAC("6","7",hp[3],ar)
        AMAC("8","9",hp[4],ar)   AMAC("10","11",hp[5],ar) AMAC("12","13",hp[6],ar) AMAC("14","15",hp[7],ar)
        AMAC("16","17",hp[8],ar) AMAC("18","19",hp[9],ar) AMAC("20","21",hp[10],ar) AMAC("22","23",hp[11],ar)
        AMAC("24","25",hp[12],ar) AMAC("26","27",hp[13],ar) AMAC("28","29",hp[14],ar) AMAC("30","31",hp[15],ar)
        AMAC("32","33",hp[0],az)  AMAC("34","35",hp[1],az)  AMAC("36","37",hp[2],az)  AMAC("38","39",hp[3],az)
        AMAC("40","41",hp[4],az)  AMAC("42","43",hp[5],az)  AMAC("44","45",hp[6],az)  AMAC("46","47",hp[7],az)
        AMAC("48","49",hp[8],az)  AMAC("50","51",hp[9],az)  AMAC("52","53",hp[10],az) AMAC("54","55",hp[11],az)
        AMAC("56","57",hp[12],az) AMAC("58","59",hp[13],az) AMAC("60","61",hp[14],az) AMAC("62","63",hp[15],az)
        AMAC("64","65",hp[0],an)  AMAC("66","67",hp[1],an)  AMAC("68","69",hp[2],an)  AMAC("70","71",hp[3],an)
        AMAC("72","73",hp[4],an)  AMAC("74","75",hp[5],an)  AMAC("76","77",hp[6],an)  AMAC("78","79",hp[7],an)
        AMAC("80","81",hp[8],an)  AMAC("82","83",hp[9],an)  AMAC("84","85",hp[10],an) AMAC("86","87",hp[11],an)
        AMAC("88","89",hp[12],an) AMAC("90","91",hp[13],an) AMAC("92","93",hp[14],an) AMAC("94","95",hp[15],an)
        float sr = ar.x + ar.y, sz = az.x + az.y, sn = an.x + an.y;
        sr += DPPF(sr, QP_XOR1); sr += DPPF(sr, QP_XOR2);
        sz += DPPF(sz, QP_XOR1); sz += DPPF(sz, QP_XOR2);
        sn += DPPF(sn, QP_XOR1); sn += DPPF(sn, QP_XOR2);
        const float gir = DPPF(gi_cur, QP_B0);
        const float giz = DPPF(gi_cur, QP_B1);
        const float gin = DPPF(gi_cur, QP_B2);
        const float r = 1.f / (1.f + __expf(-(gir + sr + bhr)));
        const float z = 1.f / (1.f + __expf(-(giz + sz + bhz)));
        const float nx = gin + r * (sn + bhn);
        const float n = 1.f - 2.f / (1.f + __expf(2.f * nx));   // tanh
        const float hn = n + z * (hold - n);
        if (q == 0) h_l[cur ^ 1][hslot] = hn;
        if (q == 3) {
            if (seq_out) {
                const int l = dir ? (LQn - 1 - step) : step;
                seq_out[((size_t)(b * LQn + l)) * (2 * Hn) + dir * Hn + j] = hn;
            }
            hlast = hn;
        }
        cur ^= 1;
        // LDS-only barrier: do NOT drain vmcnt (gi prefetch + seq stores stay in flight)
        asm volatile("s_waitcnt lgkmcnt(0)\n\ts_barrier" ::: "memory");
    };

    // 2-slot gi register ring
    float gA, gB;
#define GLD(d, s) { d = ldq ? gptr[(long)(s) * sstride] : 0.f; }
    GLD(gA, 0)
    GLD(gB, 1)
    for (int s0 = 0; s0 < LQn; s0 += 2) {
        gstep(gA, s0);
        { const int sn2 = (s0 + 2 < LQn) ? s0 + 2 : LQn - 1; GLD(gA, sn2) }
        gstep(gB, s0 + 1);
        { const int sn2 = (s0 + 3 < LQn) ? s0 + 3 : LQn - 1; GLD(gB, sn2) }
    }
#undef GLD
    if (final_out && q == 3) final_out[b * 2 * Hn + dir * Hn + j] = hlast;
}

// =================== K5: classifier MLP ===================
__global__ __launch_bounds__(256) void k_cls(
    const float* __restrict__ cls_in,
    const float* __restrict__ c1w, const float* __restrict__ c1b,
    const float* __restrict__ c2w, const float* __restrict__ c2b,
    const float* __restrict__ c3w, const float* __restrict__ c3b,
    float* __restrict__ out)
{
    __shared__ float ci[256], y1[128], y2[64];
    const int b = blockIdx.x, tid = threadIdx.x;
    ci[tid] = cls_in[b * 256 + tid];
    __syncthreads();
    if (tid < 128) { float a = c1b[tid]; for (int i = 0; i < 256; ++i) a += ci[i] * c1w[i * 128 + tid]; y1[tid] = a; }
    __syncthreads();
    if (tid < 64)  { float a = c2b[tid]; for (int i = 0; i < 128; ++i) a += y1[i] * c2w[i * 64 + tid];  y2[tid] = a; }
    __syncthreads();
    if (tid < 6)   { float a = c3b[tid]; for (int i = 0; i < 64; ++i)  a += y2[i] * c3w[i * 6 + tid];   out[b * 6 + tid] = a; }
}

// =================== launch ===================
extern "C" void kernel_launch(void* const* d_in, const int* in_sizes, int n_in,
                              void* d_out, int out_size, void* d_ws, size_t ws_size,
                              hipStream_t stream)
{
    const float* x        = (const float*)d_in[0];
    const float* tsteps   = (const float*)d_in[1];
    const float* qtimes   = (const float*)d_in[2];
    const float* lin_w    = (const float*)d_in[3];
    const float* lin_b    = (const float*)d_in[4];
    const float* per_w    = (const float*)d_in[5];
    const float* per_b    = (const float*)d_in[6];
    const float* wq       = (const float*)d_in[7];
    const float* bq       = (const float*)d_in[8];
    const float* wk       = (const float*)d_in[9];
    const float* bk       = (const float*)d_in[10];
    const float* wo       = (const float*)d_in[11];
    const float* bo       = (const float*)d_in[12];
    const float* g0_wih   = (const float*)d_in[13];
    const float* g0_whh   = (const float*)d_in[14];
    const float* g0_bih   = (const float*)d_in[15];
    const float* g0_bhh   = (const float*)d_in[16];
    const float* g1_wih   = (const float*)d_in[17];
    const float* g1_whh   = (const float*)d_in[18];
    const float* g1_bih   = (const float*)d_in[19];
    const float* g1_bhh   = (const float*)d_in[20];
    const float* c1w      = (const float*)d_in[21];
    const float* c1b      = (const float*)d_in[22];
    const float* c2w      = (const float*)d_in[23];
    const float* c2b      = (const float*)d_in[24];
    const float* c3w      = (const float*)d_in[25];
    const float* c3b      = (const float*)d_in[26];
    float* out = (float*)d_out;
    float* ws  = (float*)d_ws;

    float* Cws   = ws + WS_C;
    float* Wt    = ws + WS_WT;
    float* bias2 = ws + WS_B2;
    float* clsin = ws + WS_CLS;
    float* g0buf = ws + WS_G0;
    float* qpB   = ws + WS_QPB;
    float* basB  = ws + WS_BAS;
    float* accP  = ws + WS_ACCP;
    float* sPb   = ws + WS_SP;
    float* gibuf = ws + WS_GI;

    // --- score-polynomial coefficients (parallel pipeline) ---
    k_basis<<<1, 128, 0, stream>>>(per_w, per_b, basB);
    k_qp<<<128, 128, 0, stream>>>(qtimes, lin_w, lin_b, per_w, per_b, wq, bq, qpB);
    k_qtc<<<128, 128, 0, stream>>>(qpB, wk, bk, lin_w, lin_b, basB, Cws);

    k_fuse<<<99, 256, 0, stream>>>(g0_wih, wo, bo, g0_bih, Wt, bias2);
    k_attn<<<256, 512, 0, stream>>>(x, tsteps, Cws, accP, sPb);

    // layer 0: gi = att @ Wt^T + bias2 (att assembled in-GEMM from accP/sP)
    k_gemm_att<<<dim3(128, 12), 256, 0, stream>>>(accP, sPb, Wt, bias2, gibuf);
    k_gru<<<128, 512, 0, stream>>>(gibuf, g0_whh, g0_bhh, g0buf, nullptr);

    // layer 1: gi = g0 @ wih^T + bih   (A: 8192x256, B: 768x256)
    k_gemm_nt<<<dim3(128, 12), 256, 0, stream>>>(g0buf, g1_wih, g1_bih, gibuf, 768, 256);
    k_gru<<<128, 512, 0, stream>>>(gibuf, g1_whh, g1_bhh, nullptr, clsin);

    k_cls<<<64, 256, 0, stream>>>(clsin, c1w, c1b, c2w, c2b, c3w, c3b, out);
}

// Round 11
// 325.236 us; speedup vs baseline: 1.4225x; 1.4225x over previous
//
#include <hip/hip_runtime.h>
#include <math.h>

#define Bn   64
#define Ln   4096
#define LQn  128
#define Dn   32
#define ETn  128
#define Hn   128
#define G3n  384
#define NDEG 12

typedef __attribute__((ext_vector_type(2))) float f32x2;

// DPP helpers (VALU cross-lane, no LDS pipe)
#define DPPF(x, ctrl) __int_as_float(__builtin_amdgcn_update_dpp(0, __float_as_int(x), (ctrl), 0xF, 0xF, true))
#define QP_XOR1 0xB1   // quad_perm [1,0,3,2]
#define QP_XOR2 0x4E   // quad_perm [2,3,0,1]
#define QP_B0   0x00
#define QP_B1   0x55
#define QP_B2   0xAA
#define QP_B3   0xFF

// odd sin polynomial, |x| <= ~0.5, err < 5e-9
__device__ __forceinline__ float sin_poly(float x) {
    const float x2 = x * x;
    float r = -1.9841270114e-04f;
    r = fmaf(r, x2,  8.3333337680e-03f);
    r = fmaf(r, x2, -1.6666667163e-01f);
    return fmaf(r * x2, x, x);
}
// even cos polynomial, |x| <= ~0.5, err < 3e-10
__device__ __forceinline__ float cos_poly(float x) {
    const float x2 = x * x;
    float r =  2.4801587642e-05f;
    r = fmaf(r, x2, -1.3888888899e-03f);
    r = fmaf(r, x2,  4.1666667908e-02f);
    r = fmaf(r, x2, -5.0000000000e-01f);
    return fmaf(r, x2, 1.0f);
}

// ---- workspace layout (float offsets) ----
#define WS_C    0                          // 128*12
#define WS_WT   4096                       // 768*32
#define WS_B2   (WS_WT + 768*32)           // 768 (pad 1024)
#define WS_CLS  (WS_B2 + 1024)             // 64*256
#define WS_G0   (WS_CLS + Bn*2*Hn)         // 8192*256  (transient aliases below)
#define WS_GI   (WS_G0 + Bn*LQn*2*Hn)      // 8192*768
// transient aliases inside WS_G0 (dead before the region's next use):
#define WS_ACCP WS_G0                      // 4*8192*32 (k_attn -> k_gemm_att)
#define WS_SP   (WS_G0 + 1048576)          // 4*8192

// =================== K1: merged score-polynomial coefficients ===================
// One block per q: basis (recomputed per block, trivial), qe, qp, qt, C[q][*].
__global__ __launch_bounds__(128) void k_coef(
    const float* __restrict__ qtimes, const float* __restrict__ lin_w,
    const float* __restrict__ lin_b, const float* __restrict__ per_w,
    const float* __restrict__ per_b, const float* __restrict__ wq,
    const float* __restrict__ bq, const float* __restrict__ wk,
    const float* __restrict__ bk, float* __restrict__ C)
{
    __shared__ float qe[ETn], qp_l[ETn], qt_l[ETn], bas[NDEG * 128], red[96], qbk_red[32];
    const int q = blockIdx.x, tid = threadIdx.x;
    // basis[d][j] = pw_j^d/d! * phase(pb_j, d)
    if (tid < ETn - 1) {
        const float w = per_w[tid], bb = per_b[tid];
        const float sb = sin_poly(bb), cb = cos_poly(bb);
        float wp = 1.f;
#pragma unroll
        for (int d = 0; d < NDEG; ++d) {
            const float sd = ((d & 3) == 0) ? sb : ((d & 3) == 1) ? cb : ((d & 3) == 2) ? -sb : -cb;
            bas[d * 128 + tid] = wp * sd;
            wp *= w / (float)(d + 1);
        }
    }
    const float t = qtimes[q];
    qe[tid] = (tid == 0) ? fmaf(t, lin_w[0], lin_b[0])
                         : sin_poly(fmaf(t, per_w[tid - 1], per_b[tid - 1]));
    __syncthreads();
    {   // qp[e] = sum_i qe[i]*wq[i][e] + bq[e]  (coalesced across e)
        float a = bq[tid];
#pragma unroll 16
        for (int i = 0; i < ETn; ++i) a = fmaf(qe[i], wq[i * ETn + tid], a);
        qp_l[tid] = a;
    }
    __syncthreads();
    {   // qt[c] = qp . wk[c][:]  (per-thread float4 row)
        const float4* wk4 = (const float4*)(wk + (size_t)tid * ETn);
        const float4* qp4 = (const float4*)qp_l;
        float a = 0.f;
#pragma unroll
        for (int k = 0; k < 32; ++k) {
            const float4 w4 = wk4[k], p4 = qp4[k];
            a += w4.x * p4.x + w4.y * p4.y + w4.z * p4.z + w4.w * p4.w;
        }
        qt_l[tid] = a;
    }
    __syncthreads();
    if (tid < 96) {
        const int d = tid >> 3, g = tid & 7;
        float p = 0.f;
        for (int j = g; j < ETn - 1; j += 8) p = fmaf(qt_l[j + 1], bas[d * 128 + j], p);
        red[tid] = p;
    } else {
        const int g2 = tid - 96;
        float p = 0.f;
#pragma unroll
        for (int k = 0; k < 4; ++k) p = fmaf(qp_l[g2 + 32 * k], bk[g2 + 32 * k], p);
        qbk_red[g2] = p;
    }
    __syncthreads();
    if (tid < NDEG) {
        const int d = tid;
        float s = red[d * 8 + 0] + red[d * 8 + 1] + red[d * 8 + 2] + red[d * 8 + 3]
                + red[d * 8 + 4] + red[d * 8 + 5] + red[d * 8 + 6] + red[d * 8 + 7];
        if (d == 0) {
            float qbk = 0.f;
#pragma unroll
            for (int k = 0; k < 32; ++k) qbk += qbk_red[k];
            s += qt_l[0] * lin_b[0] + qbk;
        }
        if (d == 1) s += qt_l[0] * lin_w[0];
        C[q * NDEG + d] = s * 0.08838834764831845f;   // 1/sqrt(128)
    }
}

// =================== K1d: fold wo (+bo) into layer-0 wih (float4 dots) ===================
__global__ __launch_bounds__(256) void k_fuse(
    const float* __restrict__ wih, const float* __restrict__ wo,
    const float* __restrict__ bo, const float* __restrict__ bih,
    float* __restrict__ Wt, float* __restrict__ bias2)
{
    const int t = blockIdx.x * 256 + threadIdx.x;
    if (t < 768 * 32) {
        const int o = t >> 5, d = t & 31;
        const float4* wr4 = (const float4*)(wih + (size_t)o * 128);
        const float4* wc4 = (const float4*)(wo + (size_t)d * 128);
        float a = 0.f;
#pragma unroll
        for (int k = 0; k < 32; ++k) {
            const float4 r4 = wr4[k], c4 = wc4[k];
            a += r4.x * c4.x + r4.y * c4.y + r4.z * c4.z + r4.w * c4.w;
        }
        Wt[t] = a;
    } else if (t < 768 * 33) {
        const int o = t - 768 * 32;
        const float4* wr4 = (const float4*)(wih + (size_t)o * 128);
        const float4* bo4 = (const float4*)bo;
        float a = bih[o];
#pragma unroll
        for (int k = 0; k < 32; ++k) {
            const float4 r4 = wr4[k], b4 = bo4[k];
            a += r4.x * b4.x + r4.y * b4.y + r4.z * b4.z + r4.w * b4.w;
        }
        bias2[o] = a;
    }
}

// =================== K2: attention — LDS-broadcast x, pk_fma PV ===================
// grid 256 = (b, lsplit); 512 threads = (i = tid&3, qt = (tid>>2)&31, ls2 = tid>>7).
// x staged per-64-l chunk in LDS (reg-prefetched); same-address ds_read = free broadcast.
__global__ __launch_bounds__(512, 1) void k_attn(
    const float* __restrict__ x, const float* __restrict__ tsteps,
    const float* __restrict__ Cc, float* __restrict__ accP, float* __restrict__ sP)
{
    __shared__ float4 xls[4 * 64 * 8];          // [ls2][row 64][col 8] float4 = 32 KB
    __shared__ float  slab[4][128][36];         // 73.7 KB
    const int tid = threadIdx.x;
    const int b = blockIdx.x >> 2, lsplit = blockIdx.x & 3;
    const int i = tid & 3, qt = (tid >> 2) & 31, ls2 = tid >> 7;
    const int qown = 4 * qt + i;
    const int u = tid & 127;                    // lane index within ls2 group

    float c[NDEG];
#pragma unroll
    for (int d = 0; d < NDEG; ++d) c[d] = Cc[qown * NDEG + d];

    const int l0 = lsplit * 1024 + ls2 * 256;
    const float4* tg4 = (const float4*)(tsteps + (size_t)b * Ln + l0);
    const float4* xg  = (const float4*)(x + ((size_t)b * Ln + l0) * Dn);   // 8 float4/row

    f32x2 acc2[4][4];
#pragma unroll
    for (int m = 0; m < 4; ++m)
#pragma unroll
        for (int e = 0; e < 4; ++e) { acc2[m][e].x = 0.f; acc2[m][e].y = 0.f; }
    float s_own = 0.f;

    // prefetch chunk 0 (64 rows = 512 float4 per ls2; 4 per lane)
    float4 xr[4];
#pragma unroll
    for (int w = 0; w < 4; ++w) xr[w] = xg[u + 128 * w];

    for (int ch = 0; ch < 4; ++ch) {
        __syncthreads();                         // previous chunk fully consumed
#pragma unroll
        for (int w = 0; w < 4; ++w) xls[ls2 * 512 + u + 128 * w] = xr[w];
        __syncthreads();                         // staged chunk visible
        if (ch < 3) {
            const int off = (ch + 1) * 512;
#pragma unroll
            for (int w = 0; w < 4; ++w) xr[w] = xg[off + u + 128 * w];
        }
        const float4* xrow = &xls[ls2 * 512];
        for (int k = 0; k < 16; ++k) {
            const float4 t4 = tg4[ch * 16 + k];
#pragma unroll
            for (int jj = 0; jj < 4; ++jj) {
                const float t = (jj == 0) ? t4.x : (jj == 1) ? t4.y : (jj == 2) ? t4.z : t4.w;
                float sc = c[NDEG - 1];
#pragma unroll
                for (int d = NDEG - 2; d >= 0; --d) sc = fmaf(sc, t, c[d]);
                const float pe = __expf(sc);
                s_own += pe;
                const float p0 = DPPF(pe, QP_B0);
                const float p1 = DPPF(pe, QP_B1);
                const float p2 = DPPF(pe, QP_B2);
                const float p3 = DPPF(pe, QP_B3);
                const int lrow = (k * 4 + jj) * 8;
                const float4 xa = xrow[lrow + 2 * i];       // broadcast read
                const float4 xb = xrow[lrow + 2 * i + 1];
                f32x2 xa0; xa0.x = xa.x; xa0.y = xa.y;
                f32x2 xa1; xa1.x = xa.z; xa1.y = xa.w;
                f32x2 xb0; xb0.x = xb.x; xb0.y = xb.y;
                f32x2 xb1; xb1.x = xb.z; xb1.y = xb.w;
#define PKA(m, pv) { f32x2 pp; pp.x = (pv); pp.y = (pv); \
    acc2[m][0] = __builtin_elementwise_fma(pp, xa0, acc2[m][0]); \
    acc2[m][1] = __builtin_elementwise_fma(pp, xa1, acc2[m][1]); \
    acc2[m][2] = __builtin_elementwise_fma(pp, xb0, acc2[m][2]); \
    acc2[m][3] = __builtin_elementwise_fma(pp, xb1, acc2[m][3]); }
                PKA(0, p0) PKA(1, p1) PKA(2, p2) PKA(3, p3)
#undef PKA
            }
        }
    }
    __syncthreads();
#pragma unroll
    for (int m = 0; m < 4; ++m) {
        float4 f4a, f4b;
        f4a.x = acc2[m][0].x; f4a.y = acc2[m][0].y; f4a.z = acc2[m][1].x; f4a.w = acc2[m][1].y;
        f4b.x = acc2[m][2].x; f4b.y = acc2[m][2].y; f4b.z = acc2[m][3].x; f4b.w = acc2[m][3].y;
        *(float4*)&slab[ls2][4 * qt + m][8 * i]     = f4a;
        *(float4*)&slab[ls2][4 * qt + m][8 * i + 4] = f4b;
    }
    slab[ls2][qown][32] = s_own;
    __syncthreads();
    const int q = tid & 127, part = tid >> 7;
#pragma unroll
    for (int j = 0; j < 2; ++j) {
        const int off = (part * 2 + j) * 4;
        float4 r  = *(float4*)&slab[0][q][off];
        float4 r1 = *(float4*)&slab[1][q][off];
        float4 r2 = *(float4*)&slab[2][q][off];
        float4 r3 = *(float4*)&slab[3][q][off];
        r.x += r1.x + r2.x + r3.x; r.y += r1.y + r2.y + r3.y;
        r.z += r1.z + r2.z + r3.z; r.w += r1.w + r2.w + r3.w;
        *(float4*)&accP[((((size_t)lsplit * Bn + b) * LQn + q) * 32) + off] = r;
    }
    if (part == 0) {
        sP[((size_t)lsplit * Bn + b) * LQn + q] =
            slab[0][q][32] + slab[1][q][32] + slab[2][q][32] + slab[3][q][32];
    }
}

// =================== K3a: GEMM layer-0: A = (sum_ls accP)/(sum_ls sP), K=32, pk core ===================
__global__ __launch_bounds__(256) void k_gemm_att(
    const float* __restrict__ accP, const float* __restrict__ sP,
    const float* __restrict__ Bm, const float* __restrict__ bias,
    float* __restrict__ Cm)
{
    __shared__ float4 A_l[64 * 8];
    __shared__ float4 B_l[64 * 8];
    const int tid = threadIdx.x;
    const int m0 = blockIdx.x * 64, n0 = blockIdx.y * 64;
    const int r0 = (tid >> 4) << 2, c0 = (tid & 15) << 2;
    f32x2 acc2[4][4];
#pragma unroll
    for (int a = 0; a < 4; ++a)
#pragma unroll
        for (int bb = 0; bb < 4; ++bb) { acc2[a][bb].x = 0.f; acc2[a][bb].y = 0.f; }
    const float4* Ag = (const float4*)accP;
    const float4* Bg = (const float4*)Bm;

#pragma unroll
    for (int w = 0; w < 2; ++w) {
        const int idx = tid + w * 256;
        const int row = idx >> 3, c4 = idx & 7;
        const int sc = (c4 + row + (row >> 2)) & 7;
        const int m = m0 + row;
        float4 a0 = Ag[(size_t)m * 8 + c4];
        float4 a1 = Ag[((size_t)8192  + m) * 8 + c4];
        float4 a2 = Ag[((size_t)16384 + m) * 8 + c4];
        float4 a3 = Ag[((size_t)24576 + m) * 8 + c4];
        const float inv = 1.f / (sP[m] + sP[8192 + m] + sP[16384 + m] + sP[24576 + m]);
        float4 av;
        av.x = (a0.x + a1.x + a2.x + a3.x) * inv;
        av.y = (a0.y + a1.y + a2.y + a3.y) * inv;
        av.z = (a0.z + a1.z + a2.z + a3.z) * inv;
        av.w = (a0.w + a1.w + a2.w + a3.w) * inv;
        A_l[row * 8 + sc] = av;
        B_l[row * 8 + sc] = Bg[(size_t)(n0 + row) * 8 + c4];
    }
    __syncthreads();
#pragma unroll
    for (int k4 = 0; k4 < 8; ++k4) {
        float4 av[4], bv[4];
#pragma unroll
        for (int j = 0; j < 4; ++j) {
            const int ra = r0 + j;
            av[j] = A_l[ra * 8 + ((k4 + ra + (ra >> 2)) & 7)];
        }
#pragma unroll
        for (int j = 0; j < 4; ++j) {
            const int rb = c0 + j;
            bv[j] = B_l[rb * 8 + ((k4 + rb + (rb >> 2)) & 7)];
        }
#pragma unroll
        for (int ri = 0; ri < 4; ++ri) {
            f32x2 alo; alo.x = av[ri].x; alo.y = av[ri].y;
            f32x2 ahi; ahi.x = av[ri].z; ahi.y = av[ri].w;
#pragma unroll
            for (int ci = 0; ci < 4; ++ci) {
                f32x2 blo; blo.x = bv[ci].x; blo.y = bv[ci].y;
                f32x2 bhi; bhi.x = bv[ci].z; bhi.y = bv[ci].w;
                acc2[ri][ci] = __builtin_elementwise_fma(alo, blo, acc2[ri][ci]);
                acc2[ri][ci] = __builtin_elementwise_fma(ahi, bhi, acc2[ri][ci]);
            }
        }
    }
#pragma unroll
    for (int ri = 0; ri < 4; ++ri) {
        float4 o4;
        o4.x = acc2[ri][0].x + acc2[ri][0].y + bias[n0 + c0 + 0];
        o4.y = acc2[ri][1].x + acc2[ri][1].y + bias[n0 + c0 + 1];
        o4.z = acc2[ri][2].x + acc2[ri][2].y + bias[n0 + c0 + 2];
        o4.w = acc2[ri][3].x + acc2[ri][3].y + bias[n0 + c0 + 3];
        *(float4*)&Cm[(size_t)(m0 + r0 + ri) * 768 + n0 + c0] = o4;
    }
}

// =================== K3b: tiled f32 GEMM  C = A(MxK) @ B(NxK)^T + bias, pk core ===================
__global__ __launch_bounds__(256) void k_gemm_nt(
    const float* __restrict__ A, const float* __restrict__ Bm,
    const float* __restrict__ bias, float* __restrict__ Cm,
    int N, int K)
{
    __shared__ float4 A_l[64 * 8];
    __shared__ float4 B_l[64 * 8];
    const int tid = threadIdx.x;
    const int m0 = blockIdx.x * 64, n0 = blockIdx.y * 64;
    const int r0 = (tid >> 4) << 2, c0 = (tid & 15) << 2;
    const int K4 = K >> 2;
    f32x2 acc2[4][4];
#pragma unroll
    for (int a = 0; a < 4; ++a)
#pragma unroll
        for (int bb = 0; bb < 4; ++bb) { acc2[a][bb].x = 0.f; acc2[a][bb].y = 0.f; }
    const float4* Ag = (const float4*)A;
    const float4* Bg = (const float4*)Bm;

    for (int k0 = 0; k0 < K4; k0 += 8) {
        __syncthreads();
#pragma unroll
        for (int w = 0; w < 2; ++w) {
            const int idx = tid + w * 256;
            const int row = idx >> 3, c4 = idx & 7;
            const int sc = (c4 + row + (row >> 2)) & 7;
            A_l[row * 8 + sc] = Ag[(size_t)(m0 + row) * K4 + k0 + c4];
            B_l[row * 8 + sc] = Bg[(size_t)(n0 + row) * K4 + k0 + c4];
        }
        __syncthreads();
#pragma unroll
        for (int k4 = 0; k4 < 8; ++k4) {
            float4 av[4], bv[4];
#pragma unroll
            for (int j = 0; j < 4; ++j) {
                const int ra = r0 + j;
                av[j] = A_l[ra * 8 + ((k4 + ra + (ra >> 2)) & 7)];
            }
#pragma unroll
            for (int j = 0; j < 4; ++j) {
                const int rb = c0 + j;
                bv[j] = B_l[rb * 8 + ((k4 + rb + (rb >> 2)) & 7)];
            }
#pragma unroll
            for (int ri = 0; ri < 4; ++ri) {
                f32x2 alo; alo.x = av[ri].x; alo.y = av[ri].y;
                f32x2 ahi; ahi.x = av[ri].z; ahi.y = av[ri].w;
#pragma unroll
                for (int ci = 0; ci < 4; ++ci) {
                    f32x2 blo; blo.x = bv[ci].x; blo.y = bv[ci].y;
                    f32x2 bhi; bhi.x = bv[ci].z; bhi.y = bv[ci].w;
                    acc2[ri][ci] = __builtin_elementwise_fma(alo, blo, acc2[ri][ci]);
                    acc2[ri][ci] = __builtin_elementwise_fma(ahi, bhi, acc2[ri][ci]);
                }
            }
        }
    }
#pragma unroll
    for (int ri = 0; ri < 4; ++ri) {
        float4 o4;
        o4.x = acc2[ri][0].x + acc2[ri][0].y + bias[n0 + c0 + 0];
        o4.y = acc2[ri][1].x + acc2[ri][1].y + bias[n0 + c0 + 1];
        o4.z = acc2[ri][2].x + acc2[ri][2].y + bias[n0 + c0 + 2];
        o4.w = acc2[ri][3].x + acc2[ri][3].y + bias[n0 + c0 + 3];
        *(float4*)&Cm[(size_t)(m0 + r0 + ri) * N + n0 + c0] = o4;
    }
}

// =================== K4: GRU recurrence — R6 structure (best measured: 89 µs) ===================
// 256 threads: (j = tid>>1 in [0,128), q = tid&1 = 64-wide h-slice). One block per (b,dir).
__global__ __launch_bounds__(256, 1) void k_gru(
    const float* __restrict__ gi, const float* __restrict__ whh,
    const float* __restrict__ bhh, float* __restrict__ seq_out,
    float* __restrict__ final_out)
{
    __shared__ float h_l[2][Hn];
    const int tid = threadIdx.x;
    const int b = blockIdx.x >> 1, dir = blockIdx.x & 1;
    const int j = tid >> 1, q = tid & 1;

    // weights: w{r,z,n}[k] = whh[dir][g*128+j][64q + 2k .. +1], k=0..31
    f32x2 wr[32], wz[32], wn[32];
    {
        const float* wb = whh + ((size_t)dir * G3n + j) * Hn + 64 * q;
        const f32x2* p0 = (const f32x2*)(wb);
        const f32x2* p1 = (const f32x2*)(wb + (size_t)128 * Hn);
        const f32x2* p2 = (const f32x2*)(wb + (size_t)256 * Hn);
#pragma unroll
        for (int k = 0; k < 32; ++k) { wr[k] = p0[k]; wz[k] = p1[k]; wn[k] = p2[k]; }
    }
    const float bhr = bhh[dir * G3n + j];
    const float bhz = bhh[dir * G3n + 128 + j];
    const float bhn = bhh[dir * G3n + 256 + j];

    if (tid < Hn) { h_l[0][tid] = 0.f; h_l[1][tid] = 0.f; }
    __syncthreads();

    const long sstride = dir ? -768 : 768;
    const float* gptr = gi + (size_t)b * LQn * 768 + dir * G3n + j
                        + (size_t)(dir ? LQn - 1 : 0) * 768;

    int cur = 0;
    float hlast = 0.f;

    auto gstep = [&](const float gir, const float giz, const float gin,
                     const int step) {
        const float hold = h_l[cur][j];
        const float4* hb = (const float4*)(&h_l[cur][q * 64]);
        f32x2 ar = {0.f, 0.f}, az = {0.f, 0.f}, an = {0.f, 0.f};
        f32x2 br = {0.f, 0.f}, bz = {0.f, 0.f}, bn = {0.f, 0.f};
#pragma unroll
        for (int cc = 0; cc < 16; ++cc) {
            float4 hv = hb[cc];
            f32x2 h01; h01.x = hv.x; h01.y = hv.y;
            f32x2 h23; h23.x = hv.z; h23.y = hv.w;
            asm("v_pk_fma_f32 %0, %1, %2, %0" : "+v"(ar) : "v"(wr[2 * cc]),     "v"(h01));
            asm("v_pk_fma_f32 %0, %1, %2, %0" : "+v"(az) : "v"(wz[2 * cc]),     "v"(h01));
            asm("v_pk_fma_f32 %0, %1, %2, %0" : "+v"(an) : "v"(wn[2 * cc]),     "v"(h01));
            asm("v_pk_fma_f32 %0, %1, %2, %0" : "+v"(br) : "v"(wr[2 * cc + 1]), "v"(h23));
            asm("v_pk_fma_f32 %0, %1, %2, %0" : "+v"(bz) : "v"(wz[2 * cc + 1]), "v"(h23));
            asm("v_pk_fma_f32 %0, %1, %2, %0" : "+v"(bn) : "v"(wn[2 * cc + 1]), "v"(h23));
        }
        float sr = (ar.x + br.x) + (ar.y + br.y);
        float sz = (az.x + bz.x) + (az.y + bz.y);
        float sn = (an.x + bn.x) + (an.y + bn.y);
        sr += DPPF(sr, QP_XOR1);
        sz += DPPF(sz, QP_XOR1);
        sn += DPPF(sn, QP_XOR1);
        const float r = 1.f / (1.f + __expf(-(gir + sr + bhr)));
        const float z = 1.f / (1.f + __expf(-(giz + sz + bhz)));
        const float nx = gin + r * (sn + bhn);
        const float n = 1.f - 2.f / (1.f + __expf(2.f * nx));   // tanh
        const float hn = n + z * (hold - n);
        if (q == 0) {
            h_l[cur ^ 1][j] = hn;
            if (seq_out) {
                const int l = dir ? (LQn - 1 - step) : step;
                seq_out[((size_t)(b * LQn + l)) * (2 * Hn) + dir * Hn + j] = hn;
            }
        }
        hlast = hn;
        cur ^= 1;
        __syncthreads();
    };

    // 4-deep gi register ring: distance issue->consume = 4 steps
    float gA[3], gB[3], gC[3], gD[3];
#define GLD(dst, s) { const long o = (long)(s) * sstride; \
    dst[0] = gptr[o]; dst[1] = gptr[o + 128]; dst[2] = gptr[o + 256]; }
    GLD(gA, 0) GLD(gB, 1) GLD(gC, 2) GLD(gD, 3)
    for (int s0 = 0; s0 < LQn; s0 += 4) {
        gstep(gA[0], gA[1], gA[2], s0);
        { const int sn2 = (s0 + 4 < LQn) ? s0 + 4 : LQn - 1; GLD(gA, sn2) }
        gstep(gB[0], gB[1], gB[2], s0 + 1);
        { const int sn2 = (s0 + 5 < LQn) ? s0 + 5 : LQn - 1; GLD(gB, sn2) }
        gstep(gC[0], gC[1], gC[2], s0 + 2);
        { const int sn2 = (s0 + 6 < LQn) ? s0 + 6 : LQn - 1; GLD(gC, sn2) }
        gstep(gD[0], gD[1], gD[2], s0 + 3);
        { const int sn2 = (s0 + 7 < LQn) ? s0 + 7 : LQn - 1; GLD(gD, sn2) }
    }
#undef GLD
    if (final_out && q == 0) final_out[b * 2 * Hn + dir * Hn + j] = hlast;
}

// =================== K5: classifier MLP ===================
__global__ __launch_bounds__(256) void k_cls(
    const float* __restrict__ cls_in,
    const float* __restrict__ c1w, const float* __restrict__ c1b,
    const float* __restrict__ c2w, const float* __restrict__ c2b,
    const float* __restrict__ c3w, const float* __restrict__ c3b,
    float* __restrict__ out)
{
    __shared__ float ci[256], y1[128], y2[64];
    const int b = blockIdx.x, tid = threadIdx.x;
    ci[tid] = cls_in[b * 256 + tid];
    __syncthreads();
    if (tid < 128) { float a = c1b[tid]; for (int i = 0; i < 256; ++i) a += ci[i] * c1w[i * 128 + tid]; y1[tid] = a; }
    __syncthreads();
    if (tid < 64)  { float a = c2b[tid]; for (int i = 0; i < 128; ++i) a += y1[i] * c2w[i * 64 + tid];  y2[tid] = a; }
    __syncthreads();
    if (tid < 6)   { float a = c3b[tid]; for (int i = 0; i < 64; ++i)  a += y2[i] * c3w[i * 6 + tid];   out[b * 6 + tid] = a; }
}

// =================== launch ===================
extern "C" void kernel_launch(void* const* d_in, const int* in_sizes, int n_in,
                              void* d_out, int out_size, void* d_ws, size_t ws_size,
                              hipStream_t stream)
{
    const float* x        = (const float*)d_in[0];
    const float* tsteps   = (const float*)d_in[1];
    const float* qtimes   = (const float*)d_in[2];
    const float* lin_w    = (const float*)d_in[3];
    const float* lin_b    = (const float*)d_in[4];
    const float* per_w    = (const float*)d_in[5];
    const float* per_b    = (const float*)d_in[6];
    const float* wq       = (const float*)d_in[7];
    const float* bq       = (const float*)d_in[8];
    const float* wk       = (const float*)d_in[9];
    const float* bk       = (const float*)d_in[10];
    const float* wo       = (const float*)d_in[11];
    const float* bo       = (const float*)d_in[12];
    const float* g0_wih   = (const float*)d_in[13];
    const float* g0_whh   = (const float*)d_in[14];
    const float* g0_bih   = (const float*)d_in[15];
    const float* g0_bhh   = (const float*)d_in[16];
    const float* g1_wih   = (const float*)d_in[17];
    const float* g1_whh   = (const float*)d_in[18];
    const float* g1_bih   = (const float*)d_in[19];
    const float* g1_bhh   = (const float*)d_in[20];
    const float* c1w      = (const float*)d_in[21];
    const float* c1b      = (const float*)d_in[22];
    const float* c2w      = (const float*)d_in[23];
    const float* c2b      = (const float*)d_in[24];
    const float* c3w      = (const float*)d_in[25];
    const float* c3b      = (const float*)d_in[26];
    float* out = (float*)d_out;
    float* ws  = (float*)d_ws;

    float* Cws   = ws + WS_C;
    float* Wt    = ws + WS_WT;
    float* bias2 = ws + WS_B2;
    float* clsin = ws + WS_CLS;
    float* g0buf = ws + WS_G0;
    float* accP  = ws + WS_ACCP;
    float* sPb   = ws + WS_SP;
    float* gibuf = ws + WS_GI;

    k_coef<<<128, 128, 0, stream>>>(qtimes, lin_w, lin_b, per_w, per_b, wq, bq, wk, bk, Cws);
    k_fuse<<<99, 256, 0, stream>>>(g0_wih, wo, bo, g0_bih, Wt, bias2);
    k_attn<<<256, 512, 0, stream>>>(x, tsteps, Cws, accP, sPb);

    // layer 0: gi = att @ Wt^T + bias2 (att assembled in-GEMM from accP/sP)
    k_gemm_att<<<dim3(128, 12), 256, 0, stream>>>(accP, sPb, Wt, bias2, gibuf);
    k_gru<<<128, 256, 0, stream>>>(gibuf, g0_whh, g0_bhh, g0buf, nullptr);

    // layer 1: gi = g0 @ wih^T + bih   (A: 8192x256, B: 768x256)
    k_gemm_nt<<<dim3(128, 12), 256, 0, stream>>>(g0buf, g1_wih, g1_bih, gibuf, 768, 256);
    k_gru<<<128, 256, 0, stream>>>(gibuf, g1_whh, g1_bhh, nullptr, clsin);

    k_cls<<<64, 256, 0, stream>>>(clsin, c1w, c1b, c2w, c2b, c3w, c3b, out);
}